// Round 8
// baseline (90.222 us; speedup 1.0000x reference)
//
#include <hip/hip_runtime.h>

#define N 4096
#define F 64
#define H 8
#define W1S (2 * F + 1)   // 129
#define NSTRIPE 32        // column stripes of 128
#define NBAND 16          // row bands of 256   -> 512 blocks

// Single fused kernel. Block b: stripe s = b>>4 (cols s*128..+127),
// band rb = b&15 (rows rb*256..+255).
// Phase 1: column sums of A[band, stripe] -> partial[b][128], arrive cnt[s].
// Phase 2: spin until cnt[s]==16 (stripe-local sync; all 512 blocks are
//          co-resident at 2/CU so no deadlock).
// Phase 3: sum_w -> bks[128][8]; ajs[256][8] for this band's rows (LDS).
// Phase 4: out[i][j] = b2[0] + sum_k relu(ajs[i][k]+bks[j][k])*W2[0][k]
//          for 256x128 tile, coalesced float4 stores.
__global__ __launch_bounds__(256, 2) void fused_all(
    const float* __restrict__ A, const float* __restrict__ emb,
    const float* __restrict__ W1, const float* __restrict__ b1,
    const float* __restrict__ W2, const float* __restrict__ b2,
    unsigned* __restrict__ cnt, float* __restrict__ partial,
    float* __restrict__ out)
{
    __shared__ float4 ps[8][32];        // phase-1 partial reduce
    __shared__ float ajs[256][12];      // 48B row stride (float4-aligned)
    __shared__ float bks[128][12];

    const int t  = threadIdx.x;
    const int s  = blockIdx.x >> 4;     // stripe
    const int rb = blockIdx.x & 15;     // row band
    const int j0 = s * 128;
    const int i0 = rb * 256;

    // ---- Phase 1: column sums of A[i0..i0+255, j0..j0+127] ----
    {
        int c4 = t & 31;                // 4-col group
        int rg = t >> 5;                // 8 row groups x 32 rows
        const float* p = A + (size_t)(i0 + rg * 32) * N + j0 + c4 * 4;
        float4 acc = make_float4(0.f, 0.f, 0.f, 0.f);
#pragma unroll 16
        for (int r = 0; r < 32; ++r) {
            float4 v = *(const float4*)(p + (size_t)r * N);
            acc.x += v.x; acc.y += v.y; acc.z += v.z; acc.w += v.w;
        }
        ps[rg][c4] = acc;
    }
    __syncthreads();
    if (t < 32) {
        float4 tot = make_float4(0.f, 0.f, 0.f, 0.f);
#pragma unroll
        for (int g = 0; g < 8; ++g) {
            float4 v = ps[g][t];
            tot.x += v.x; tot.y += v.y; tot.z += v.z; tot.w += v.w;
        }
        *(float4*)(partial + (size_t)blockIdx.x * 128 + t * 4) = tot;
    }
    __syncthreads();    // partial stores drained (vmcnt) before arrival

    // ---- Phase 2: stripe-local barrier ----
    if (t == 0) {
        __threadfence();                      // release: partial visible device-wide
        atomicAdd(&cnt[s], 1u);
        while (__hip_atomic_load(&cnt[s], __ATOMIC_RELAXED,
                                 __HIP_MEMORY_SCOPE_AGENT) < (unsigned)NBAND) {
            __builtin_amdgcn_s_sleep(16);
        }
        __threadfence();                      // acquire: invalidate stale caches
    }
    __syncthreads();

    // ---- Phase 3: sum_w + bks (threads 0-127), ajs x2 rows (threads 128-255) ----
    if (t < 128) {
        float tot = 0.f;
#pragma unroll
        for (int r = 0; r < NBAND; ++r)
            tot += partial[(size_t)(s * NBAND + r) * 128 + t];
        int j = j0 + t;
        float sw = (tot - A[(size_t)j * N + j]) * (1.0f / (float)(N - 1));
        float bv[H];
#pragma unroll
        for (int k = 0; k < H; ++k) bv[k] = sw * W1[k * W1S + 2 * F];
#pragma unroll
        for (int f = 0; f < F; ++f) {
            float e = emb[(size_t)f * N + j];
#pragma unroll
            for (int k = 0; k < H; ++k) bv[k] += e * W1[k * W1S + F + f];
        }
#pragma unroll
        for (int k = 0; k < H; ++k) bks[t][k] = bv[k];
    } else {
        int u = t - 128;
        float a0[H], a1[H];
#pragma unroll
        for (int k = 0; k < H; ++k) { a0[k] = b1[k]; a1[k] = b1[k]; }
#pragma unroll
        for (int f = 0; f < F; ++f) {
            float e0 = emb[(size_t)f * N + i0 + u];
            float e1 = emb[(size_t)f * N + i0 + 128 + u];
#pragma unroll
            for (int k = 0; k < H; ++k) {
                a0[k] += e0 * W1[k * W1S + f];
                a1[k] += e1 * W1[k * W1S + f];
            }
        }
#pragma unroll
        for (int k = 0; k < H; ++k) { ajs[u][k] = a0[k]; ajs[128 + u][k] = a1[k]; }
    }
    __syncthreads();

    // ---- Phase 4: fused outer product + relu-dot, 256 rows x 128 cols ----
    {
        int tx = t & 31;
        int ty = t >> 5;                 // 8 groups x 16 rows -> 128 rows per pass
        int j  = j0 + tx * 4;

        float w2[H];
#pragma unroll
        for (int k = 0; k < H; ++k) w2[k] = W2[k];   // W2[0][k]
        float b20 = b2[0];

        float bkr[4][H];
#pragma unroll
        for (int c = 0; c < 4; ++c) {
            float4 lo = *(const float4*)&bks[tx * 4 + c][0];
            float4 hi = *(const float4*)&bks[tx * 4 + c][4];
            bkr[c][0] = lo.x; bkr[c][1] = lo.y; bkr[c][2] = lo.z; bkr[c][3] = lo.w;
            bkr[c][4] = hi.x; bkr[c][5] = hi.y; bkr[c][6] = hi.z; bkr[c][7] = hi.w;
        }

#pragma unroll 2
        for (int half = 0; half < 2; ++half) {
#pragma unroll
            for (int r = 0; r < 16; ++r) {
                int row = half * 128 + ty * 16 + r;
                float a[H];
                float4 lo = *(const float4*)&ajs[row][0];   // broadcast
                float4 hi = *(const float4*)&ajs[row][4];
                a[0] = lo.x; a[1] = lo.y; a[2] = lo.z; a[3] = lo.w;
                a[4] = hi.x; a[5] = hi.y; a[6] = hi.z; a[7] = hi.w;

                float res[4];
#pragma unroll
                for (int c = 0; c < 4; ++c) {
                    float acc = b20;
#pragma unroll
                    for (int k = 0; k < H; ++k) {
                        float tt = a[k] + bkr[c][k];
                        acc += fmaxf(tt, 0.f) * w2[k];
                    }
                    res[c] = acc;
                }
                *(float4*)(out + (size_t)(i0 + row) * N + j) =
                    make_float4(res[0], res[1], res[2], res[3]);
            }
        }
    }
}

extern "C" void kernel_launch(void* const* d_in, const int* in_sizes, int n_in,
                              void* d_out, int out_size, void* d_ws, size_t ws_size,
                              hipStream_t stream) {
    const float* adj = (const float*)d_in[0];   // (1, N, N)
    const float* emb = (const float*)d_in[1];   // (1, F, N)
    const float* W1  = (const float*)d_in[2];   // (H, 2F+1)
    const float* b1  = (const float*)d_in[3];   // (H,)
    const float* W2  = (const float*)d_in[4];   // (8, H)
    const float* b2  = (const float*)d_in[5];   // (8,)
    float* out = (float*)d_out;

    unsigned* cnt  = (unsigned*)d_ws;                       // 32 counters
    float* partial = (float*)((char*)d_ws + 512);           // 512*128 floats = 256 KB

    hipMemsetAsync(d_ws, 0, 512, stream);                   // zero counters (capturable)
    fused_all<<<dim3(NSTRIPE * NBAND), 256, 0, stream>>>(adj, emb, W1, b1, W2, b2,
                                                         cnt, partial, out);
}

// Round 9
// 50.222 us; speedup vs baseline: 1.7965x; 1.7965x over previous
//
#include <hip/hip_runtime.h>

#define N 4096
#define F 64
#define H 8
#define W1S (2 * F + 1)   // 129
#define PCH 128           // partial chunks (32 rows each)

// ---------------------------------------------------------------------------
// Kernel 1: partial column sums of A. grid (4, 128) = 512 blocks, block 256.
// Block (x,y): cols x*1024 + t*4 (float4), rows y*32..y*32+31.
// partial[y][col], [128][4096] = 2 MB (L2/LLC-resident for K2).
// ---------------------------------------------------------------------------
__global__ __launch_bounds__(256) void colsum_partial(const float* __restrict__ A,
                                                      float* __restrict__ partial) {
    int c4 = blockIdx.x * 256 + threadIdx.x;
    int r0 = blockIdx.y * 32;
    const float* p = A + (size_t)r0 * N + (size_t)c4 * 4;
    float4 acc = make_float4(0.f, 0.f, 0.f, 0.f);
#pragma unroll 16
    for (int r = 0; r < 32; ++r) {
        float4 v = *(const float4*)(p + (size_t)r * N);
        acc.x += v.x; acc.y += v.y; acc.z += v.z; acc.w += v.w;
    }
    *(float4*)(partial + (size_t)blockIdx.y * N + (size_t)c4 * 4) = acc;
}

// ---------------------------------------------------------------------------
// Kernel 2: per 128-row x 256-col output tile (grid 16 x 32 = 512 blocks):
//   A1: thread t owns column j0+t: sums its 128 partial chunks in-register
//       (per-wave 256B coalesced, L2-resident).
//   A2: thread t computes bk[j0+t][0..7] directly (sum_w in-register, no
//       handoff) -> LDS; threads 0..127 then compute aj[i0+t][0..7] -> LDS.
//   B : tx=t&63 -> 4 cols (bk regs), ty=t>>6 -> 32 rows; out = b2 +
//       sum_k relu(aj+bk)*w2. aj LDS reads are wave-broadcast (conflict-free);
//       wave stores are 1KB fully contiguous float4.
// ---------------------------------------------------------------------------
__global__ __launch_bounds__(256) void fuse_tile(const float* __restrict__ A,
                                                 const float* __restrict__ emb,
                                                 const float* __restrict__ W1,
                                                 const float* __restrict__ b1,
                                                 const float* __restrict__ W2,
                                                 const float* __restrict__ b2,
                                                 const float* __restrict__ partial,
                                                 float* __restrict__ out) {
    __shared__ float ajs[128][12];    // 48B row stride, float4-aligned
    __shared__ float bks[256][12];

    const int t  = threadIdx.x;
    const int j0 = blockIdx.x * 256;
    const int i0 = blockIdx.y * 128;

    // ---- A1: full column sum for col j0+t ----
    float s = 0.f;
    {
        const float* pp = partial + j0 + t;
#pragma unroll 16
        for (int p = 0; p < PCH; ++p) s += pp[(size_t)p * N];
    }

    // ---- A2a: bk for col j0+t (sum_w stays in-register) ----
    {
        int j = j0 + t;
        float sw = (s - A[(size_t)j * N + j]) * (1.0f / (float)(N - 1));
        float bv[H];
#pragma unroll
        for (int k = 0; k < H; ++k) bv[k] = sw * W1[k * W1S + 2 * F];
#pragma unroll
        for (int f = 0; f < F; ++f) {
            float e = emb[(size_t)f * N + j];
#pragma unroll
            for (int k = 0; k < H; ++k) bv[k] += e * W1[k * W1S + F + f];
        }
#pragma unroll
        for (int k = 0; k < H; ++k) bks[t][k] = bv[k];
    }

    // ---- A2b: aj for rows i0..i0+127 (threads 0-127) ----
    if (t < 128) {
        int i = i0 + t;
        float av[H];
#pragma unroll
        for (int k = 0; k < H; ++k) av[k] = b1[k];
#pragma unroll
        for (int f = 0; f < F; ++f) {
            float e = emb[(size_t)f * N + i];
#pragma unroll
            for (int k = 0; k < H; ++k) av[k] += e * W1[k * W1S + f];
        }
#pragma unroll
        for (int k = 0; k < H; ++k) ajs[t][k] = av[k];
    }
    __syncthreads();

    // ---- B: fused outer product + relu-dot ----
    int tx = t & 63;
    int ty = t >> 6;                  // 4 groups x 32 rows
    int j  = j0 + tx * 4;

    float w2[H];
#pragma unroll
    for (int k = 0; k < H; ++k) w2[k] = W2[k];   // W2[0][k]
    float b20 = b2[0];

    float bkr[4][H];
#pragma unroll
    for (int c = 0; c < 4; ++c) {
        float4 lo = *(const float4*)&bks[tx * 4 + c][0];
        float4 hi = *(const float4*)&bks[tx * 4 + c][4];
        bkr[c][0] = lo.x; bkr[c][1] = lo.y; bkr[c][2] = lo.z; bkr[c][3] = lo.w;
        bkr[c][4] = hi.x; bkr[c][5] = hi.y; bkr[c][6] = hi.z; bkr[c][7] = hi.w;
    }

#pragma unroll
    for (int r = 0; r < 32; ++r) {
        int row = ty * 32 + r;
        float a[H];
        float4 lo = *(const float4*)&ajs[row][0];   // wave-broadcast
        float4 hi = *(const float4*)&ajs[row][4];
        a[0] = lo.x; a[1] = lo.y; a[2] = lo.z; a[3] = lo.w;
        a[4] = hi.x; a[5] = hi.y; a[6] = hi.z; a[7] = hi.w;

        float res[4];
#pragma unroll
        for (int c = 0; c < 4; ++c) {
            float acc = b20;
#pragma unroll
            for (int k = 0; k < H; ++k) {
                float tt = a[k] + bkr[c][k];
                acc += fmaxf(tt, 0.f) * w2[k];
            }
            res[c] = acc;
        }
        *(float4*)(out + (size_t)(i0 + row) * N + j) =
            make_float4(res[0], res[1], res[2], res[3]);
    }
}

extern "C" void kernel_launch(void* const* d_in, const int* in_sizes, int n_in,
                              void* d_out, int out_size, void* d_ws, size_t ws_size,
                              hipStream_t stream) {
    const float* adj = (const float*)d_in[0];   // (1, N, N)
    const float* emb = (const float*)d_in[1];   // (1, F, N)
    const float* W1  = (const float*)d_in[2];   // (H, 2F+1)
    const float* b1  = (const float*)d_in[3];   // (H,)
    const float* W2  = (const float*)d_in[4];   // (8, H)
    const float* b2  = (const float*)d_in[5];   // (8,)
    float* out = (float*)d_out;

    float* partial = (float*)d_ws;              // PCH * N floats = 2 MB

    colsum_partial<<<dim3(4, PCH), 256, 0, stream>>>(adj, partial);
    fuse_tile<<<dim3(N / 256, N / 128), 256, 0, stream>>>(adj, emb, W1, b1, W2, b2,
                                                          partial, out);
}

// Round 10
// 49.802 us; speedup vs baseline: 1.8116x; 1.0084x over previous
//
#include <hip/hip_runtime.h>

#define N 4096
#define F 64
#define H 8
#define W1S (2 * F + 1)   // 129
#define PCH 128           // partial chunks (32 rows each)

// ---------------------------------------------------------------------------
// Kernel 1: partial column sums of A. grid (4, 128) = 512 blocks, block 256.
// partial[y][col], [128][4096] = 2 MB (L2/LLC-resident for K2).
// ---------------------------------------------------------------------------
__global__ __launch_bounds__(256) void colsum_partial(const float* __restrict__ A,
                                                      float* __restrict__ partial) {
    int c4 = blockIdx.x * 256 + threadIdx.x;
    int r0 = blockIdx.y * 32;
    const float* p = A + (size_t)r0 * N + (size_t)c4 * 4;
    float4 acc = make_float4(0.f, 0.f, 0.f, 0.f);
#pragma unroll 16
    for (int r = 0; r < 32; ++r) {
        float4 v = *(const float4*)(p + (size_t)r * N);
        acc.x += v.x; acc.y += v.y; acc.z += v.z; acc.w += v.w;
    }
    *(float4*)(partial + (size_t)blockIdx.y * N + (size_t)c4 * 4) = acc;
}

// ---------------------------------------------------------------------------
// Kernel 2: per 128x128 output tile (grid 32x32 = 1024 blocks = 4/CU):
// Phase A (balanced halves, no internal sync):
//   threads 0-127:  col j=j0+t: bk F-term accum (64 emb loads) interleaved by
//                   the scheduler with the 128 partial-chunk loads; sw applied
//                   last (no serial dep) -> bks LDS.
//   threads 128-255: row i=i0+(t-128): aj = b1 + E.W1a -> ajs LDS.
// Phase B: tx=t&31 -> 4 cols (bk in regs), ty=t>>5 -> 16 rows;
//   aj LDS reads wave-broadcast; stores 2x512B contiguous per wave instr.
// ---------------------------------------------------------------------------
__global__ __launch_bounds__(256) void fuse_tile(const float* __restrict__ A,
                                                 const float* __restrict__ emb,
                                                 const float* __restrict__ W1,
                                                 const float* __restrict__ b1,
                                                 const float* __restrict__ W2,
                                                 const float* __restrict__ b2,
                                                 const float* __restrict__ partial,
                                                 float* __restrict__ out) {
    __shared__ float ajs[128][12];    // 48B row stride, float4-aligned
    __shared__ float bks[128][12];

    const int t  = threadIdx.x;
    const int j0 = blockIdx.x * 128;
    const int i0 = blockIdx.y * 128;

    if (t < 128) {
        int j = j0 + t;
        // F-term accumulation (emb loads) — independent of partial loads
        float bv[H];
#pragma unroll
        for (int k = 0; k < H; ++k) bv[k] = 0.f;
#pragma unroll
        for (int f = 0; f < F; ++f) {
            float e = emb[(size_t)f * N + j];
#pragma unroll
            for (int k = 0; k < H; ++k) bv[k] += e * W1[k * W1S + F + f];
        }
        // column sum of A via partial chunks (L2-resident)
        float s = 0.f;
        {
            const float* pp = partial + j;
#pragma unroll 32
            for (int p = 0; p < PCH; ++p) s += pp[(size_t)p * N];
        }
        float sw = (s - A[(size_t)j * N + j]) * (1.0f / (float)(N - 1));
#pragma unroll
        for (int k = 0; k < H; ++k) bks[t][k] = bv[k] + sw * W1[k * W1S + 2 * F];
    } else {
        int i = i0 + (t - 128);
        float av[H];
#pragma unroll
        for (int k = 0; k < H; ++k) av[k] = b1[k];
#pragma unroll
        for (int f = 0; f < F; ++f) {
            float e = emb[(size_t)f * N + i];
#pragma unroll
            for (int k = 0; k < H; ++k) av[k] += e * W1[k * W1S + f];
        }
#pragma unroll
        for (int k = 0; k < H; ++k) ajs[t - 128][k] = av[k];
    }
    __syncthreads();

    // ---- B: fused outer product + relu-dot ----
    int tx = t & 31;
    int ty = t >> 5;                  // 8 groups x 16 rows
    int j  = j0 + tx * 4;

    float w2[H];
#pragma unroll
    for (int k = 0; k < H; ++k) w2[k] = W2[k];   // W2[0][k]
    float b20 = b2[0];

    float bkr[4][H];
#pragma unroll
    for (int c = 0; c < 4; ++c) {
        float4 lo = *(const float4*)&bks[tx * 4 + c][0];
        float4 hi = *(const float4*)&bks[tx * 4 + c][4];
        bkr[c][0] = lo.x; bkr[c][1] = lo.y; bkr[c][2] = lo.z; bkr[c][3] = lo.w;
        bkr[c][4] = hi.x; bkr[c][5] = hi.y; bkr[c][6] = hi.z; bkr[c][7] = hi.w;
    }

#pragma unroll
    for (int r = 0; r < 16; ++r) {
        int row = ty * 16 + r;
        float a[H];
        float4 lo = *(const float4*)&ajs[row][0];   // wave-broadcast
        float4 hi = *(const float4*)&ajs[row][4];
        a[0] = lo.x; a[1] = lo.y; a[2] = lo.z; a[3] = lo.w;
        a[4] = hi.x; a[5] = hi.y; a[6] = hi.z; a[7] = hi.w;

        float res[4];
#pragma unroll
        for (int c = 0; c < 4; ++c) {
            float acc = b20;
#pragma unroll
            for (int k = 0; k < H; ++k) {
                float tt = a[k] + bkr[c][k];
                acc += fmaxf(tt, 0.f) * w2[k];
            }
            res[c] = acc;
        }
        *(float4*)(out + (size_t)(i0 + row) * N + j) =
            make_float4(res[0], res[1], res[2], res[3]);
    }
}

extern "C" void kernel_launch(void* const* d_in, const int* in_sizes, int n_in,
                              void* d_out, int out_size, void* d_ws, size_t ws_size,
                              hipStream_t stream) {
    const float* adj = (const float*)d_in[0];   // (1, N, N)
    const float* emb = (const float*)d_in[1];   // (1, F, N)
    const float* W1  = (const float*)d_in[2];   // (H, 2F+1)
    const float* b1  = (const float*)d_in[3];   // (H,)
    const float* W2  = (const float*)d_in[4];   // (8, H)
    const float* b2  = (const float*)d_in[5];   // (8,)
    float* out = (float*)d_out;

    float* partial = (float*)d_ws;              // PCH * N floats = 2 MB

    colsum_partial<<<dim3(4, PCH), 256, 0, stream>>>(adj, partial);
    fuse_tile<<<dim3(N / 128, N / 128), 256, 0, stream>>>(adj, emb, W1, b1, W2, b2,
                                                          partial, out);
}